// Round 13
// baseline (450.233 us; speedup 1.0000x reference)
//
#include <hip/hip_runtime.h>
#include <math.h>

// GCN: 4x GCNConv (self-loops, sym-norm) + BN+GELU between, log_softmax at end.
// CSR (by dst) built per call; aggregation = atomic-free gather; aggregate on the
// narrow side of each layer (linearity); BN bias-cancellation drops b1..b3.
// R1: hierarchical scan, fused BN-stats, fused log_softmax. 806 -> 622 us.
// R4: dinv-prescale + unrolled gather. 622 -> 553 us.
// R6: bucket-sort CSR build, all writes coalesced. 553 -> 524 us.
// R7: count_kernel + N-scans deleted (per-bucket LDS degree count). 524 -> 450 us.
// R9: gemm 4-col tiles REGRESSED (450 -> 582): fewer threads + barriers = stalls.
// R10: thread-per-row gemm (VGPR acc, scalar-K$ W, no LDS/barriers). 582 -> 433 us.
// R11: L4 table padded to 64B lines, 4-lane float4 gather in agg_lsm. 433 -> 411 us.
// R12: (a) ebuf packed to u32 (dstloc<<23|src; N<2^23, dstloc<512) — halves C2
//      write + D read; (b) bucket_offsets+csr_fill merged into one per-bucket
//      kernel (single ebuf read, -1 launch); (c) bn_gelu<64> pass DELETED —
//      BN+GELU folded into gemm_l4's load loop (-51MB traffic, -1 launch).
//      Rejected: fusing gemms into agg epilogues (per-lane W kills scalar-K$,
//      +13-51M VMEM issues >> 25MB saved — R9 lesson).

#define TPB 256
#define K_BUCK 256
#define CCHUNK 4096   // edges per chunk in C1/C2
#define DCAP 8192     // per-bucket CSR LDS capacity (32 KB); mean 6250, +24 sigma
#define SRC_BITS 23
#define SRC_MASK 0x7FFFFF
constexpr float BN_EPS = 1e-5f;

#define SCHUNK 2048  // elements per scan block (256 thr x 8)

__global__ void scan_reduce_kernel(const int* __restrict__ in, int* __restrict__ bsum, int n) {
    int base = blockIdx.x * SCHUNK;
    int s = 0;
    for (int j = threadIdx.x; j < SCHUNK; j += TPB) {
        int i = base + j;
        s += (i < n) ? in[i] : 0;
    }
#pragma unroll
    for (int d = 32; d; d >>= 1) s += __shfl_down(s, d);
    __shared__ int ws[TPB / 64];
    if ((threadIdx.x & 63) == 0) ws[threadIdx.x >> 6] = s;
    __syncthreads();
    if (threadIdx.x == 0) {
        int t = 0;
        for (int w = 0; w < TPB / 64; ++w) t += ws[w];
        bsum[blockIdx.x] = t;
    }
}

// single wave: exclusive-scan bsum[0..nb)
__global__ void scan_bsum_kernel(int* __restrict__ bsum, int nb) {
    __shared__ int carry;
    int lane = threadIdx.x;
    if (lane == 0) carry = 0;
    __syncthreads();
    for (int base = 0; base < nb; base += 64) {
        int i = base + lane;
        int v = (i < nb) ? bsum[i] : 0;
        int incl = v;
#pragma unroll
        for (int d = 1; d < 64; d <<= 1) {
            int u = __shfl_up(incl, d);
            if (lane >= d) incl += u;
        }
        if (i < nb) bsum[i] = carry + incl - v;
        int tot = __shfl(incl, 63);
        __syncthreads();
        if (lane == 0) carry += tot;
        __syncthreads();
    }
}

// block-local scan + apply block prefix
__global__ void scan_apply_kernel(const int* __restrict__ in, const int* __restrict__ bsum,
                                  int* __restrict__ out, int n) {
    int base = blockIdx.x * SCHUNK;
    int tid = threadIdx.x;
    int lane = tid & 63, wave = tid >> 6;
    int i0 = base + tid * 8;
    int v[8];
    int tsum = 0;
#pragma unroll
    for (int k = 0; k < 8; ++k) {
        int i = i0 + k;
        v[k] = (i < n) ? in[i] : 0;
        tsum += v[k];
    }
    int incl = tsum;
#pragma unroll
    for (int d = 1; d < 64; d <<= 1) {
        int u = __shfl_up(incl, d);
        if (lane >= d) incl += u;
    }
    int lexcl = incl - tsum;
    __shared__ int wsum[TPB / 64];
    if (lane == 63) wsum[wave] = incl;
    __syncthreads();
    int wbase = 0;
    for (int w = 0; w < wave; ++w) wbase += wsum[w];
    int off = bsum[blockIdx.x] + wbase + lexcl;
#pragma unroll
    for (int k = 0; k < 8; ++k) {
        int i = i0 + k;
        if (i < n) out[i] = off;
        off += v[k];
    }
}

// ---------------- bucket-sort CSR build (all writes coalesced) ----------------

// C1: per-chunk histogram over K_BUCK dst-buckets -> hist[bucket * nb + chunk].
// Block 0 also zeroes the BN stats accumulators (runs well before any stats use).
__global__ void bucket_hist_kernel(const int* __restrict__ dst, int* __restrict__ hist,
                                   float* __restrict__ stats, int e, int n, int nb) {
    __shared__ int lh[K_BUCK];
    for (int i = threadIdx.x; i < K_BUCK; i += TPB) lh[i] = 0;
    if (blockIdx.x == 0)
        for (int i = threadIdx.x; i < 384; i += TPB) stats[i] = 0.0f;
    __syncthreads();
    int base = blockIdx.x * CCHUNK;
    int end = min(base + CCHUNK, e);
    int div = (n + K_BUCK - 1) / K_BUCK;
    for (int i = base + threadIdx.x; i < end; i += TPB) atomicAdd(&lh[dst[i] / div], 1);
    __syncthreads();
    for (int b = threadIdx.x; b < K_BUCK; b += TPB) hist[b * nb + blockIdx.x] = lh[b];
}

// C2: re-read chunk, group PACKED edges (dstloc<<23 | src) by bucket in LDS,
// flush runs to ebuf coalesced. hbase = exclusive scan of hist (bucket-major).
__global__ void bucket_scatter_kernel(const int* __restrict__ src, const int* __restrict__ dst,
                                      const int* __restrict__ hist, const int* __restrict__ hbase,
                                      unsigned int* __restrict__ ebuf, int e, int n, int nb) {
    __shared__ int lbase[K_BUCK];
    __shared__ int eoff[K_BUCK];
    __shared__ int lcur[K_BUCK];
    __shared__ unsigned int stage[CCHUNK];
    __shared__ unsigned char sb[CCHUNK];
    int t = threadIdx.x;  // TPB == K_BUCK
    int blk = blockIdx.x;
    int c = hist[t * nb + blk];
    lbase[t] = hbase[t * nb + blk];
    lcur[t] = 0;
    eoff[t] = c;
    __syncthreads();
    for (int d = 1; d < K_BUCK; d <<= 1) {  // inclusive scan of counts
        int v = (t >= d) ? eoff[t - d] : 0;
        __syncthreads();
        eoff[t] += v;
        __syncthreads();
    }
    eoff[t] -= c;  // exclusive
    __syncthreads();
    int base = blk * CCHUNK;
    int end = min(base + CCHUNK, e);
    int div = (n + K_BUCK - 1) / K_BUCK;
    for (int i = base + t; i < end; i += TPB) {
        int d = dst[i];
        int b = d / div;
        unsigned int w = ((unsigned int)(d - b * div) << SRC_BITS) | (unsigned int)src[i];
        int p = atomicAdd(&lcur[b], 1);
        int sp = eoff[b] + p;
        stage[sp] = w;
        sb[sp] = (unsigned char)b;
    }
    __syncthreads();
    int cnt_here = end - base;
    for (int j = t; j < cnt_here; j += TPB) {
        int b = sb[j];
        ebuf[lbase[b] + (j - eoff[b])] = stage[j];  // coalesced within runs
    }
}

// R12: merged bucket_offsets + csr_fill. One block per bucket, single ebuf read:
// LDS degree count -> wave scan -> offsets/dinv coalesced -> LDS CSR fill ->
// coalesced stream-out. segbase = ebeg = hbase[b*nb] (lexc[0]==0).
__global__ void bucket_build_kernel(const unsigned int* __restrict__ ebuf,
                                    const int* __restrict__ hbase, int* __restrict__ offsets,
                                    float* __restrict__ dinv, int* __restrict__ csr_src,
                                    int e, int n, int nb) {
    __shared__ int lcnt[512];
    __shared__ int lcur[512];
    __shared__ int lcsr[DCAP];
    int b = blockIdx.x;
    int div = (n + K_BUCK - 1) / K_BUCK;
    int lo = b * div;
    int hi = min(lo + div, n);
    int nloc = hi - lo;
    int ebeg = hbase[b * nb];
    int eend = (b == K_BUCK - 1) ? e : hbase[(b + 1) * nb];
    for (int i = threadIdx.x; i < 512; i += TPB) lcnt[i] = 0;
    __syncthreads();
    for (int j = ebeg + threadIdx.x; j < eend; j += TPB)
        atomicAdd(&lcnt[ebuf[j] >> SRC_BITS], 1);
    __syncthreads();
    if (threadIdx.x < 64) {  // wave 0: exclusive scan lcnt[0..512) -> lcur
        int l = threadIdx.x;
        int base = l * 8;
        int v[8];
        int tsum = 0;
#pragma unroll
        for (int k = 0; k < 8; ++k) { v[k] = lcnt[base + k]; tsum += v[k]; }
        int incl = tsum;
#pragma unroll
        for (int d = 1; d < 64; d <<= 1) {
            int u = __shfl_up(incl, d);
            if (l >= d) incl += u;
        }
        int off = incl - tsum;
#pragma unroll
        for (int k = 0; k < 8; ++k) { lcur[base + k] = off; off += v[k]; }
    }
    __syncthreads();
    for (int i = threadIdx.x; i < nloc; i += TPB) {
        offsets[lo + i] = ebeg + lcur[i];
        dinv[lo + i] = rsqrtf((float)(lcnt[i] + 1));  // +1 = self loop
    }
    if (b == K_BUCK - 1 && threadIdx.x == 0) offsets[n] = e;
    __syncthreads();
    for (int j = ebeg + threadIdx.x; j < eend; j += TPB) {
        unsigned int w = ebuf[j];
        int p = atomicAdd(&lcur[w >> SRC_BITS], 1);
        if (p < DCAP) lcsr[p] = (int)(w & SRC_MASK);
        else csr_src[ebeg + p] = (int)(w & SRC_MASK);  // overflow guard
    }
    __syncthreads();
    int seglen = eend - ebeg;
    int lim = min(seglen, DCAP);
    for (int j = threadIdx.x; j < lim; j += TPB) csr_src[ebeg + j] = lcsr[j];
}

// ---------------- dense transforms (R10: thread-per-row, scalar W) ----------------

// One thread per row: acc[FOUT] in VGPRs, row read as FIN/4 float4, W wave-uniform
// -> scalar K$ loads. No LDS, no barriers. Optional dinv prescale on output.
template <int FIN, int FOUT, bool DINV>
__global__ void gemm_rw_kernel(const float* __restrict__ H, const float* __restrict__ W,
                               float* __restrict__ O, const float* __restrict__ dinv, int n) {
    int row = blockIdx.x * blockDim.x + threadIdx.x;
    if (row >= n) return;
    float acc[FOUT];
#pragma unroll
    for (int c = 0; c < FOUT; ++c) acc[c] = 0.0f;
    const float4* h4 = (const float4*)(H + (size_t)row * FIN);
#pragma unroll
    for (int k = 0; k < FIN / 4; ++k) {
        float4 h = h4[k];
        const float* w = W + (size_t)(4 * k) * FOUT;
#pragma unroll
        for (int c = 0; c < FOUT; ++c) {
            acc[c] = fmaf(h.x, w[c], acc[c]);
            acc[c] = fmaf(h.y, w[FOUT + c], acc[c]);
            acc[c] = fmaf(h.z, w[2 * FOUT + c], acc[c]);
            acc[c] = fmaf(h.w, w[3 * FOUT + c], acc[c]);
        }
    }
    float sc = DINV ? dinv[row] : 1.0f;
    float4* o4 = (float4*)(O + (size_t)row * FOUT);
#pragma unroll
    for (int c = 0; c < FOUT / 4; ++c)
        o4[c] = make_float4(acc[4 * c] * sc, acc[4 * c + 1] * sc,
                            acc[4 * c + 2] * sc, acc[4 * c + 3] * sc);
}

// R12 L4: reads RAW L3 gemm output, applies BN(stats,g,be)+GELU inline per input
// element (stats indices wave-uniform -> scalar loads), then 64->10 transform,
// prescaled by dinv, stored at stride 16 (one 64B line/row).
__global__ void gemm_l4_fused_kernel(const float* __restrict__ H, const float* __restrict__ W,
                                     float* __restrict__ O, const float* __restrict__ dinv,
                                     const float* __restrict__ stats, const float* __restrict__ g,
                                     const float* __restrict__ be, int n) {
    int row = blockIdx.x * blockDim.x + threadIdx.x;
    if (row >= n) return;
    float inv_n = 1.0f / (float)n;
    float acc[10];
#pragma unroll
    for (int c = 0; c < 10; ++c) acc[c] = 0.0f;
    const float4* h4 = (const float4*)(H + (size_t)row * 64);
#pragma unroll
    for (int k = 0; k < 16; ++k) {
        float4 h = h4[k];
        float hv[4] = {h.x, h.y, h.z, h.w};
#pragma unroll
        for (int j = 0; j < 4; ++j) {
            int f = 4 * k + j;
            float mu = stats[f] * inv_n;
            float var = stats[64 + f] * inv_n - mu * mu;
            float scf = rsqrtf(var + BN_EPS) * g[f];
            float shf = be[f] - mu * scf;
            float x = fmaf(hv[j], scf, shf);
            hv[j] = 0.5f * x * (1.0f + erff(x * 0.70710678118654752f));
        }
        const float* w = W + (size_t)(4 * k) * 10;
#pragma unroll
        for (int c = 0; c < 10; ++c) {
            acc[c] = fmaf(hv[0], w[c], acc[c]);
            acc[c] = fmaf(hv[1], w[10 + c], acc[c]);
            acc[c] = fmaf(hv[2], w[20 + c], acc[c]);
            acc[c] = fmaf(hv[3], w[30 + c], acc[c]);
        }
    }
    float sc = dinv[row];
    float4* o4 = (float4*)(O + (size_t)row * 16);
    o4[0] = make_float4(acc[0] * sc, acc[1] * sc, acc[2] * sc, acc[3] * sc);
    o4[1] = make_float4(acc[4] * sc, acc[5] * sc, acc[6] * sc, acc[7] * sc);
    o4[2] = make_float4(acc[8] * sc, acc[9] * sc, 0.0f, 0.0f);
}

// Standalone BN stats: per-feature sum & sumsq over V[n,F] (L2-resident).
template <int F>
__global__ void bn_stats_kernel(const float* __restrict__ V, float* __restrict__ stats, int n) {
    constexpr int RPB = TPB / F;
    int f = threadIdx.x % F;
    int rl = threadIdx.x / F;
    float s = 0.0f, s2 = 0.0f;
    for (int r = blockIdx.x * RPB + rl; r < n; r += gridDim.x * RPB) {
        float v = V[(size_t)r * F + f];
        s += v;
        s2 = fmaf(v, v, s2);
    }
    __shared__ float sh[2 * F];
    for (int i = threadIdx.x; i < 2 * F; i += TPB) sh[i] = 0.0f;
    __syncthreads();
    atomicAdd(&sh[f], s);
    atomicAdd(&sh[F + f], s2);
    __syncthreads();
    for (int i = threadIdx.x; i < 2 * F; i += TPB) atomicAdd(&stats[i], sh[i]);
}

// ---------------- aggregation ----------------

// Gather-aggregate over dinv-PRESCALED table T' (T'[u] = T[u]*dinv[u]):
//   out[node] = dinv[node] * (sum_{u in nbr} T'[u] + T'[node])
template <int F, bool STATS>
__global__ void agg4_kernel(const float* __restrict__ T, float* __restrict__ A,
                            const float* __restrict__ dinv, const int* __restrict__ offsets,
                            const int* __restrict__ csr_src, float* __restrict__ stats, int n) {
    constexpr int G = F / 4;
    __shared__ float sh[STATS ? 2 * F : 1];
    if (STATS) {
        for (int i = threadIdx.x; i < 2 * F; i += blockDim.x) sh[i] = 0.0f;
        __syncthreads();
    }
    const float4* T4 = (const float4*)T;
    float4 ss = {0, 0, 0, 0}, s2 = {0, 0, 0, 0};
    int lane0 = -1;
    int total = n * G;
    int stride = gridDim.x * blockDim.x;
    for (int idx = blockIdx.x * blockDim.x + threadIdx.x; idx < total; idx += stride) {
        int node = idx / G;
        int lane = idx % G;
        float4 acc = T4[(size_t)node * G + lane];  // self term (prescaled)
        int s = offsets[node], e = offsets[node + 1];
        int j = s;
        for (; j + 3 < e; j += 4) {
            int u0 = csr_src[j], u1 = csr_src[j + 1], u2 = csr_src[j + 2], u3 = csr_src[j + 3];
            float4 t0 = T4[(size_t)u0 * G + lane];
            float4 t1 = T4[(size_t)u1 * G + lane];
            float4 t2 = T4[(size_t)u2 * G + lane];
            float4 t3 = T4[(size_t)u3 * G + lane];
            acc.x += (t0.x + t1.x) + (t2.x + t3.x);
            acc.y += (t0.y + t1.y) + (t2.y + t3.y);
            acc.z += (t0.z + t1.z) + (t2.z + t3.z);
            acc.w += (t0.w + t1.w) + (t2.w + t3.w);
        }
        for (; j < e; ++j) {
            int u = csr_src[j];
            float4 t = T4[(size_t)u * G + lane];
            acc.x += t.x; acc.y += t.y; acc.z += t.z; acc.w += t.w;
        }
        float di = dinv[node];
        acc.x *= di; acc.y *= di; acc.z *= di; acc.w *= di;
        ((float4*)A)[(size_t)idx] = acc;
        if (STATS) {
            ss.x += acc.x; ss.y += acc.y; ss.z += acc.z; ss.w += acc.w;
            s2.x = fmaf(acc.x, acc.x, s2.x); s2.y = fmaf(acc.y, acc.y, s2.y);
            s2.z = fmaf(acc.z, acc.z, s2.z); s2.w = fmaf(acc.w, acc.w, s2.w);
            lane0 = lane;
        }
    }
    if (STATS) {
        if (lane0 >= 0) {
            atomicAdd(&sh[lane0 * 4 + 0], ss.x); atomicAdd(&sh[lane0 * 4 + 1], ss.y);
            atomicAdd(&sh[lane0 * 4 + 2], ss.z); atomicAdd(&sh[lane0 * 4 + 3], ss.w);
            atomicAdd(&sh[F + lane0 * 4 + 0], s2.x); atomicAdd(&sh[F + lane0 * 4 + 1], s2.y);
            atomicAdd(&sh[F + lane0 * 4 + 2], s2.z); atomicAdd(&sh[F + lane0 * 4 + 3], s2.w);
        }
        __syncthreads();
        for (int i = threadIdx.x; i < 2 * F; i += blockDim.x) atomicAdd(&stats[i], sh[i]);
    }
}

// Final layer: T padded to 16 floats/row (one 64B line). 4 lanes/node, one
// float4 gather each; valid cols = 4*lane+j < 10; log_softmax via quad shfl_xor.
__global__ void agg_lsm_kernel(const float* __restrict__ T, const float* __restrict__ dinv,
                               const int* __restrict__ offsets, const int* __restrict__ csr_src,
                               const float* __restrict__ b4, float* __restrict__ out, int n) {
    int idx = blockIdx.x * blockDim.x + threadIdx.x;
    int node = idx >> 2;
    int lane = idx & 3;
    if (node >= n) return;
    const float4* T4 = (const float4*)T;
    float4 acc = T4[(size_t)node * 4 + lane];  // self (prescaled; pads masked later)
    int s = offsets[node], e = offsets[node + 1];
    int j = s;
    for (; j + 1 < e; j += 2) {
        int u0 = csr_src[j], u1 = csr_src[j + 1];
        float4 t0 = T4[(size_t)u0 * 4 + lane];
        float4 t1 = T4[(size_t)u1 * 4 + lane];
        acc.x += t0.x + t1.x; acc.y += t0.y + t1.y;
        acc.z += t0.z + t1.z; acc.w += t0.w + t1.w;
    }
    if (j < e) {
        int u = csr_src[j];
        float4 t = T4[(size_t)u * 4 + lane];
        acc.x += t.x; acc.y += t.y; acc.z += t.z; acc.w += t.w;
    }
    float di = dinv[node];
    int c0 = lane * 4;
    float v[4];
    int nv = (c0 < 10) ? min(10 - c0, 4) : 0;
#pragma unroll
    for (int k = 0; k < 4; ++k) {
        float a = (k == 0) ? acc.x : (k == 1) ? acc.y : (k == 2) ? acc.z : acc.w;
        v[k] = (k < nv) ? fmaf(di, a, b4[c0 + k]) : -1e30f;
    }
    float m = fmaxf(fmaxf(v[0], v[1]), fmaxf(v[2], v[3]));
    m = fmaxf(m, __shfl_xor(m, 1));
    m = fmaxf(m, __shfl_xor(m, 2));
    float sum = 0.0f;
#pragma unroll
    for (int k = 0; k < 4; ++k)
        if (k < nv) sum += expf(v[k] - m);
    sum += __shfl_xor(sum, 1);
    sum += __shfl_xor(sum, 2);
    float ls = m + logf(sum);
#pragma unroll
    for (int k = 0; k < 4; ++k)
        if (k < nv) out[(size_t)node * 10 + c0 + k] = v[k] - ls;
}

// ---------------- BN + GELU (kept for F=16, F=32) ----------------

template <int F, bool DINV>
__global__ void bn_gelu_kernel(float* __restrict__ V, const float* __restrict__ stats,
                               const float* __restrict__ g, const float* __restrict__ be,
                               const float* __restrict__ dinv, int n) {
    int i = blockIdx.x * blockDim.x + threadIdx.x;
    if (i >= n * F) return;
    int f = i % F;
    float inv_n = 1.0f / (float)n;
    float mu = stats[f] * inv_n;
    float var = stats[F + f] * inv_n - mu * mu;
    float sc = rsqrtf(var + BN_EPS) * g[f];
    float shf = be[f] - mu * sc;
    float x = fmaf(V[i], sc, shf);
    float y = 0.5f * x * (1.0f + erff(x * 0.70710678118654752f));
    V[i] = DINV ? y * dinv[i / F] : y;
}

static inline int cdiv(long long a, int b) { return (int)((a + b - 1) / b); }

extern "C" void kernel_launch(void* const* d_in, const int* in_sizes, int n_in,
                              void* d_out, int out_size, void* d_ws, size_t ws_size,
                              hipStream_t stream) {
    const float* x  = (const float*)d_in[0];
    const int*   ei = (const int*)d_in[1];
    const float* W1 = (const float*)d_in[2];
    const float* g1 = (const float*)d_in[4];
    const float* be1= (const float*)d_in[5];
    const float* W2 = (const float*)d_in[6];
    const float* g2 = (const float*)d_in[8];
    const float* be2= (const float*)d_in[9];
    const float* W3 = (const float*)d_in[10];
    const float* g3 = (const float*)d_in[12];
    const float* be3= (const float*)d_in[13];
    const float* W4 = (const float*)d_in[14];
    const float* b4 = (const float*)d_in[15];
    float* out = (float*)d_out;

    const int N = in_sizes[0] / 128;
    const int E = in_sizes[1] / 2;
    const int* srcI = ei;
    const int* dstI = ei + E;
    const int NBc = cdiv(E, CCHUNK);           // edge chunks
    const int HN  = K_BUCK * NBc;              // histogram entries
    const int NBh = cdiv(HN, SCHUNK);          // scan blocks for hist

    char* p = (char*)d_ws;
    auto carve = [&](size_t bytes) {
        void* q = (void*)p;
        p += (bytes + 255) & ~(size_t)255;
        return q;
    };
    int*   offsets = (int*)  carve((size_t)(N + 1) * 4);
    float* dinv    = (float*)carve((size_t)N * 4);
    int*   csr_src = (int*)  carve((size_t)E * 4);
    int*   hist    = (int*)  carve((size_t)HN * 4);
    int*   hbase   = (int*)  carve((size_t)(HN + 1) * 4);
    unsigned int* ebuf = (unsigned int*)carve((size_t)E * 4);
    int*   bsum    = (int*)  carve((size_t)(NBh + 1) * 4);
    float* stats   = (float*)carve(384 * 4);   // L1@0 (2x16), L2@128 (2x32), L3@256 (2x64)
    float* A       = (float*)carve((size_t)N * 64 * 4);
    float* B       = (float*)carve((size_t)N * 64 * 4);

    // --- bucket-sort CSR build (coalesced writes; packed u32 edges) ---
    bucket_hist_kernel<<<NBc, TPB, 0, stream>>>(dstI, hist, stats, E, N, NBc);
    scan_reduce_kernel<<<NBh, TPB, 0, stream>>>(hist, bsum, HN);
    scan_bsum_kernel<<<1, 64, 0, stream>>>(bsum, NBh);
    scan_apply_kernel<<<NBh, TPB, 0, stream>>>(hist, bsum, hbase, HN);
    bucket_scatter_kernel<<<NBc, TPB, 0, stream>>>(srcI, dstI, hist, hbase, ebuf, E, N, NBc);
    bucket_build_kernel<<<K_BUCK, TPB, 0, stream>>>(ebuf, hbase, offsets, dinv, csr_src, E, N, NBc);

    // --- L1: transform(128->16, prescaled) then aggregate(16) [stats fused in agg] ---
    gemm_rw_kernel<128, 16, true><<<cdiv(N, TPB), TPB, 0, stream>>>(x, W1, A, dinv, N);
    agg4_kernel<16, true><<<1024, TPB, 0, stream>>>(A, B, dinv, offsets, csr_src, stats + 0, N);
    bn_gelu_kernel<16, true><<<cdiv((long long)N * 16, TPB), TPB, 0, stream>>>(B, stats + 0, g1, be1, dinv, N);

    // --- L2: aggregate(16) then transform(16->32), standalone stats ---
    agg4_kernel<16, false><<<cdiv((long long)N * 4, TPB), TPB, 0, stream>>>(B, A, dinv, offsets, csr_src, nullptr, N);
    gemm_rw_kernel<16, 32, false><<<cdiv(N, TPB), TPB, 0, stream>>>(A, W2, B, nullptr, N);
    bn_stats_kernel<32><<<256, TPB, 0, stream>>>(B, stats + 128, N);
    bn_gelu_kernel<32, true><<<cdiv((long long)N * 32, TPB), TPB, 0, stream>>>(B, stats + 128, g2, be2, dinv, N);

    // --- L3: aggregate(32) then transform(32->64), standalone stats ---
    agg4_kernel<32, false><<<cdiv((long long)N * 8, TPB), TPB, 0, stream>>>(B, A, dinv, offsets, csr_src, nullptr, N);
    gemm_rw_kernel<32, 64, false><<<cdiv(N, TPB), TPB, 0, stream>>>(A, W3, B, nullptr, N);
    bn_stats_kernel<64><<<256, TPB, 0, stream>>>(B, stats + 256, N);

    // --- L4: BN+GELU fused into transform(64->10 @stride16, prescaled), then agg+lsm ---
    gemm_l4_fused_kernel<<<cdiv(N, TPB), TPB, 0, stream>>>(B, W4, A, dinv, stats + 256, g3, be3, N);
    agg_lsm_kernel<<<cdiv((long long)N * 4, TPB), TPB, 0, stream>>>(A, dinv, offsets, csr_src, b4, out, N);
}